// Round 16
// baseline (249.145 us; speedup 1.0000x reference)
//
#include <hip/hip_runtime.h>

#define PD 88      // sequences == W dim
#define TD 128     // time == T dim
#define I0 133     // layer0 input size
#define HID 24     // LSTM hidden
#define GD 96      // gates = 4*HID
#define CD 48      // channels = 2*HID
#define NH 4       // heads
#define HDIM 12    // head dim
#define KW 13      // neighborhood

typedef int int2v __attribute__((ext_vector_type(2)));

__device__ __forceinline__ int imin(int a,int b){return a<b?a:b;}
__device__ __forceinline__ int imax(int a,int b){return a>b?a:b;}

__device__ __forceinline__ float actg(float sa, float ss, float sb, float x) {
  return sa * __builtin_amdgcn_rcpf(1.f + __expf(-ss * x)) + sb;
}
// f32 -> bf16 RTNE
__device__ __forceinline__ unsigned short f2bf(float f) {
  unsigned u = __float_as_uint(f);
  u = u + 0x7fffu + ((u >> 16) & 1u);
  return (unsigned short)(u >> 16);
}
#define BLO(u) __uint_as_float((u) << 16)
#define BHI(u) __uint_as_float((u) & 0xffff0000u)

// ============ xg layer0 v6 (r13-proven: W-resident grid-stride, double-buffered x) ============
__global__ __launch_bounds__(192) void xg0_kernel(
    const float* __restrict__ x,
    const float* __restrict__ wf, const float* __restrict__ wb,
    const float* __restrict__ bif, const float* __restrict__ bhf,
    const float* __restrict__ bib, const float* __restrict__ bhb,
    float* __restrict__ xg) {
  __shared__ __align__(16) float wl[GD*I0];     // 51.1 KB
  __shared__ __align__(16) float al[2][16*136]; // 17.4 KB -> 68.5 KB total
  const int dir = blockIdx.y;
  const int tid = threadIdx.x;
  const float* W = dir ? wb : wf;
  for (int idx = tid; idx < GD*I0/4; idx += 192)
    reinterpret_cast<float4*>(wl)[idx] = reinterpret_cast<const float4*>(W)[idx];
  const int c  = tid % GD;
  const int rg = tid / GD;
  const float bias = (dir ? (bib[c]+bhb[c]) : (bif[c]+bhf[c]));
  const float* wrow = wl + c*I0;
  {
    const int tile = blockIdx.x;
    const int p = tile >> 3, tc = tile & 7;
    for (int idx = tid; idx < 16*I0; idx += 192) {
      int r = idx / I0, i = idx - r*I0;
      al[0][r*136 + i] = x[((size_t)(tc*16+r)*PD + p)*I0 + i];
    }
  }
  __syncthreads();
  int buf = 0;
#pragma unroll 1
  for (int tile = blockIdx.x; tile < 704; tile += 256, buf ^= 1) {
    const int ntile = tile + 256;
    if (ntile < 704) {
      const int np = ntile >> 3, ntc = ntile & 7;
      for (int idx = tid; idx < 16*I0; idx += 192) {
        int r = idx / I0, i = idx - r*I0;
        al[buf^1][r*136 + i] = x[((size_t)(ntc*16+r)*PD + np)*I0 + i];
      }
    }
    const int p = tile >> 3, tc = tile & 7;
    float acc[8];
#pragma unroll
    for (int r=0;r<8;r++) acc[r]=bias;
    const float* ab = al[buf] + rg*8*136;
#pragma unroll 1
    for (int i0=0; i0<132; i0+=4) {
      float w0=wrow[i0], w1=wrow[i0+1], w2=wrow[i0+2], w3=wrow[i0+3];
#pragma unroll
      for (int r=0;r<8;r++) {
        float4 a4 = *reinterpret_cast<const float4*>(&ab[r*136 + i0]);  // broadcast
        acc[r] += a4.x*w0 + a4.y*w1 + a4.z*w2 + a4.w*w3;
      }
    }
    {
      float wlast = wrow[132];
#pragma unroll
      for (int r=0;r<8;r++) acc[r] += ab[r*136 + 132]*wlast;
    }
    float* op = xg + ((size_t)dir*PD*TD + (size_t)p*TD + tc*16 + rg*8)*GD + c;
#pragma unroll
    for (int r=0;r<8;r++) op[(size_t)r*GD] = acc[r];
    __syncthreads();
  }
}

// ============ LSTM recurrence: 22 blocks x 8 waves = (4 seqs x 2 dirs) ============
// 2 recurrence waves per SIMD -> chains interleave, latency halves.
// x from global, 3-deep rolling prefetch. mode 0: out[p][t][.], mode 1: out[t][p][.]
__global__ __launch_bounds__(512) void lstm_kernel(
    const float* __restrict__ xg,
    const float* __restrict__ whf, const float* __restrict__ whb,
    float* __restrict__ out, const int mode) {
  const int wv = threadIdx.x >> 6;
  const int l  = threadIdx.x & 63;
  const int p  = blockIdx.x*4 + (wv >> 1);
  const int dir = wv & 1;
  const float* wh = dir ? whb : whf;
  const int j = l & 31;
  const bool hi = l >= 32;
  const int r1 = imin(hi ? 48+j : j,    95);   // g : i
  const int r2 = imin(hi ? 72+j : 24+j, 95);   // o : f
  float wv1[HID], wv2[HID];
#pragma unroll
  for (int k=0;k<HID;k+=4) {
    float4 a4 = *reinterpret_cast<const float4*>(wh + r1*HID + k);
    wv1[k]=a4.x; wv1[k+1]=a4.y; wv1[k+2]=a4.z; wv1[k+3]=a4.w;
    float4 b4 = *reinterpret_cast<const float4*>(wh + r2*HID + k);
    wv2[k]=b4.x; wv2[k+1]=b4.y; wv2[k+2]=b4.z; wv2[k+3]=b4.w;
  }
  const float sa1 = hi?2.f:1.f, ss1 = hi?2.f:1.f, sb1 = hi?-1.f:0.f;
  float h[HID];
#pragma unroll
  for (int k=0;k<HID;k++) h[k]=0.f;
  float c = 0.f;
  const int dt = dir ? -1 : 1;
  const float* xp = xg + ((size_t)dir*PD + p)*TD*GD;
  int t = dir ? TD-1 : 0;
  const int t1c = imin(imax(t+dt,  0), TD-1);
  const int t2c = imin(imax(t+2*dt,0), TD-1);
  float xa0 = xp[t*GD + r1],   xb0 = xp[t*GD + r2];
  float xa1 = xp[t1c*GD + r1], xb1 = xp[t1c*GD + r2];
  float xa2 = xp[t2c*GD + r1], xb2 = xp[t2c*GD + r2];
  float* optr = (mode==0) ? out + ((size_t)p*TD + t)*CD + dir*HID + l
                          : out + ((size_t)t*PD + p)*CD + dir*HID + l;
  const ptrdiff_t ostep = (mode==0) ? (ptrdiff_t)dt*CD : (ptrdiff_t)dt*PD*CD;
#pragma unroll 4
  for (int s=0; s<TD; ++s) {
    const int tp = imin(imax(t + 3*dt, 0), TD-1);   // 3-deep prefetch
    float na = xp[tp*GD + r1];
    float nb = xp[tp*GD + r2];
    float pa0=0.f,pa1=0.f,pa2=0.f,pa3=0.f, pb0=0.f,pb1=0.f,pb2=0.f,pb3=0.f;
#pragma unroll
    for (int k=0;k<HID;k+=4) {
      pa0 += wv1[k]  *h[k];   pb0 += wv2[k]  *h[k];
      pa1 += wv1[k+1]*h[k+1]; pb1 += wv2[k+1]*h[k+1];
      pa2 += wv1[k+2]*h[k+2]; pb2 += wv2[k+2]*h[k+2];
      pa3 += wv1[k+3]*h[k+3]; pb3 += wv2[k+3]*h[k+3];
    }
    float acc1 = xa0 + ((pa0+pa1)+(pa2+pa3));
    float acc2 = xb0 + ((pb0+pb1)+(pb2+pb3));
    float v1 = actg(sa1, ss1, sb1, acc1);
    float v2 = __builtin_amdgcn_rcpf(1.f + __expf(-acc2));
    int2v rg_ = __builtin_amdgcn_permlane32_swap(__float_as_int(v1), __float_as_int(v1), false, false);
    int2v ro_ = __builtin_amdgcn_permlane32_swap(__float_as_int(v2), __float_as_int(v2), false, false);
    float gg = __int_as_float(rg_.y);
    float oo = __int_as_float(ro_.y);
    c = v2*c + v1*gg;
    float th = 2.f*__builtin_amdgcn_rcpf(1.f + __expf(-2.f*c)) - 1.f;
    float hn = oo * th;
    if (l < HID) *optr = hn;
#pragma unroll
    for (int k=0;k<HID;k++)
      h[k] = __int_as_float(__builtin_amdgcn_readlane(__float_as_int(hn), k));
    optr += ostep; t += dt;
    xa0=xa1; xb0=xb1; xa1=xa2; xb1=xb2; xa2=na; xb2=nb;
  }
}

// ============ xg layer1 (r4-proven) ============
__global__ __launch_bounds__(192) void xg1_kernel(
    const float* __restrict__ h0,
    const float* __restrict__ wf, const float* __restrict__ wb,
    const float* __restrict__ bif, const float* __restrict__ bhf,
    const float* __restrict__ bib, const float* __restrict__ bhb,
    float* __restrict__ xg) {
  __shared__ float wl[192*53];
  __shared__ __align__(16) float al[32*CD];
  for (int idx = threadIdx.x; idx < 192*CD; idx += 192) {
    int cc = idx / CD, i = idx - cc*CD;
    wl[cc*53 + i] = (cc < GD) ? wf[cc*CD + i] : wb[(cc-GD)*CD + i];
  }
  const int r0 = blockIdx.x * 32;
  for (int idx = threadIdx.x; idx < 32*CD/4; idx += 192)
    reinterpret_cast<float4*>(al)[idx] =
        reinterpret_cast<const float4*>(h0 + (size_t)r0*CD)[idx];
  __syncthreads();
  const int c = threadIdx.x;
  const int dir = c >= GD;
  const int g = c - dir*GD;
  const float bias = dir ? (bib[g]+bhb[g]) : (bif[g]+bhf[g]);
  const float* wrow = wl + c*53;
  float acc[32];
#pragma unroll
  for (int r=0;r<32;r++) acc[r]=bias;
#pragma unroll 1
  for (int i0=0; i0<CD; i0+=4) {
    float w0=wrow[i0], w1=wrow[i0+1], w2=wrow[i0+2], w3=wrow[i0+3];
#pragma unroll
    for (int r=0;r<32;r++) {
      float4 a4 = *reinterpret_cast<const float4*>(&al[r*CD + i0]);  // broadcast
      acc[r] += a4.x*w0 + a4.y*w1 + a4.z*w2 + a4.w*w3;
    }
  }
  float* op = xg + (size_t)dir*PD*TD*GD + (size_t)r0*GD + g;
#pragma unroll
  for (int r=0;r<32;r++) op[(size_t)r*GD] = acc[r];
}

// ============ qkv projection (r8-proven) ============
__global__ __launch_bounds__(192) void qkv_kernel(
    const float* __restrict__ y, const float* __restrict__ wq,
    const float* __restrict__ bq,
    float* __restrict__ Qb, unsigned short* __restrict__ Kb,
    unsigned short* __restrict__ Vb) {
  __shared__ float wl[144*53];
  __shared__ __align__(16) float al[32*CD];
  for (int idx = threadIdx.x; idx < 144*CD; idx += 192) {
    int cc = idx / CD, i = idx - cc*CD;
    wl[cc*53 + i] = wq[idx];
  }
  const int r0 = blockIdx.x * 32;
  for (int idx = threadIdx.x; idx < 32*CD/4; idx += 192)
    reinterpret_cast<float4*>(al)[idx] =
        reinterpret_cast<const float4*>(y + (size_t)r0*CD)[idx];
  __syncthreads();
  const int c = threadIdx.x;
  if (c >= 144) return;
  const float bias = bq[c];
  const float* wrow = wl + c*53;
  float acc[32];
#pragma unroll
  for (int r=0;r<32;r++) acc[r]=bias;
#pragma unroll 1
  for (int i0=0; i0<CD; i0+=4) {
    float w0=wrow[i0], w1=wrow[i0+1], w2=wrow[i0+2], w3=wrow[i0+3];
#pragma unroll
    for (int r=0;r<32;r++) {
      float4 a4 = *reinterpret_cast<const float4*>(&al[r*CD + i0]);
      acc[r] += a4.x*w0 + a4.y*w1 + a4.z*w2 + a4.w*w3;
    }
  }
  if (c < CD) {
#pragma unroll
    for (int r=0;r<32;r++)
      Qb[(size_t)(r0+r)*CD + c] = acc[r]*0.28867513459481287f;
  } else if (c < 2*CD) {
    int cc = c - CD, head = cc / HDIM, jj = cc - head*HDIM;
#pragma unroll
    for (int r=0;r<32;r++)
      Kb[(size_t)(r0+r)*64 + head*16 + jj] = f2bf(acc[r]);
  } else {
    int cc = c - 2*CD, head = cc / HDIM, jj = cc - head*HDIM;
#pragma unroll
    for (int r=0;r<32;r++)
      Vb[(size_t)(r0+r)*64 + head*16 + jj] = f2bf(acc[r]);
  }
}

// ============ NATTEN 2D + fused proj (r14-proven: 24B rows, pair split, unroll 2) ============
__global__ __launch_bounds__(512) void natten_kernel(
    const float* __restrict__ Qb, const unsigned short* __restrict__ Kb,
    const unsigned short* __restrict__ Vb, const float* __restrict__ rpb,
    const float* __restrict__ wproj, const float* __restrict__ bproj,
    float* __restrict__ dst) {
  __shared__ __align__(8) unsigned kl[NH*400*6];   // 38.4 KB
  __shared__ __align__(8) unsigned vl[NH*400*6];   // 38.4 KB
  __shared__ unsigned short bl[NH*625];            // 5 KB
  __shared__ __align__(16) float aol[64*CD];       // 12.3 KB
  __shared__ float wpl[CD*49];                     // 9.4 KB -> 103.5 KB
  const int tb = blockIdx.x & 15;
  const int wb = blockIdx.x >> 4;
  const int t0 = tb*8, w0 = wb*8;
  const int ht0 = imin(imax(t0-6,0), TD-KW);
  const int hw0 = imin(imax(w0-6,0), PD-KW);
  for (int idx = threadIdx.x; idx < NH*625; idx += 512) bl[idx] = f2bf(rpb[idx]);
  for (int idx = threadIdx.x; idx < CD*CD; idx += 512) {
    int cc = idx / CD, i = idx - cc*CD;
    wpl[cc*49 + i] = wproj[idx];
  }
  for (int idx = threadIdx.x; idx < NH*400; idx += 512) {
    int h = idx / 400, pos = idx - h*400;
    int lw = pos / 20, lt = pos - lw*20;
    int gt = imin(ht0+lt, TD-1), gw = imin(hw0+lw, PD-1);
    size_t gb = ((size_t)gt*PD + gw)*64 + h*16;
    const uint2* kg = reinterpret_cast<const uint2*>(Kb + gb);
    const uint2* vg = reinterpret_cast<const uint2*>(Vb + gb);
    unsigned* kd = kl + idx*6;
    unsigned* vd = vl + idx*6;
    *reinterpret_cast<uint2*>(kd)   = kg[0];
    *reinterpret_cast<uint2*>(kd+2) = kg[1];
    *reinterpret_cast<uint2*>(kd+4) = kg[2];
    *reinterpret_cast<uint2*>(vd)   = vg[0];
    *reinterpret_cast<uint2*>(vd+2) = vg[1];
    *reinterpret_cast<uint2*>(vd+4) = vg[2];
  }
  __syncthreads();
  const int wv   = threadIdx.x >> 6;
  const int head = wv >> 1;
  const int lane = threadIdx.x & 63;
  const int e    = lane & 1;
  const int pixidx = (wv & 1)*32 + (lane >> 1);
  const int pt = pixidx & 7, pw = pixidx >> 3;   // pt-fast
  const int t = t0+pt, w = w0+pw;
  const int ts  = imin(imax(t-6,0), TD-KW);
  const int wsb = imin(imax(w-6,0), PD-KW);
  const int lt0 = ts - ht0, lw0 = wsb - hw0;
  const float* qp = Qb + ((size_t)t*PD + w)*CD + head*HDIM;
  float4 q0 = *reinterpret_cast<const float4*>(qp);
  float4 q1 = *reinterpret_cast<const float4*>(qp+4);
  float4 q2 = *reinterpret_cast<const float4*>(qp+8);
  const unsigned* kbp = kl + head*2400;
  const unsigned* vbp = vl + head*2400;
  const unsigned short* bb = bl + head*625 + (ts-t+12)*25 + (wsb-w+12);
  float sum=0.f;
  float o0=0,o1=0,o2=0,o3=0,o4=0,o5=0,o6=0,o7=0,o8=0,o9=0,o10=0,o11=0;
  for (int pp=0; pp<KW; ++pp) {
    const int ltp = lt0+pp;
    const unsigned short* br = bb + pp*25;
#pragma unroll 2
    for (int qq=e; qq<KW; qq+=2) {
      const int pos = (lw0+qq)*20 + ltp;
      const unsigned* kr = kbp + pos*6;
      uint2 ka = *reinterpret_cast<const uint2*>(kr);
      uint2 kb2= *reinterpret_cast<const uint2*>(kr+2);
      uint2 kc = *reinterpret_cast<const uint2*>(kr+4);
      float lg = __uint_as_float(((unsigned)br[qq]) << 16);
      lg += q0.x*BLO(ka.x) + q0.y*BHI(ka.x)
          + q0.z*BLO(ka.y) + q0.w*BHI(ka.y)
          + q1.x*BLO(kb2.x)+ q1.y*BHI(kb2.x)
          + q1.z*BLO(kb2.y)+ q1.w*BHI(kb2.y)
          + q2.x*BLO(kc.x) + q2.y*BHI(kc.x)
          + q2.z*BLO(kc.y) + q2.w*BHI(kc.y);
      float ex = __expf(lg);
      sum += ex;
      const unsigned* vr = vbp + pos*6;
      uint2 va = *reinterpret_cast<const uint2*>(vr);
      uint2 vb2= *reinterpret_cast<const uint2*>(vr+2);
      uint2 vc = *reinterpret_cast<const uint2*>(vr+4);
      o0  += ex*BLO(va.x);  o1  += ex*BHI(va.x);
      o2  += ex*BLO(va.y);  o3  += ex*BHI(va.y);
      o4  += ex*BLO(vb2.x); o5  += ex*BHI(vb2.x);
      o6  += ex*BLO(vb2.y); o7  += ex*BHI(vb2.y);
      o8  += ex*BLO(vc.x);  o9  += ex*BHI(vc.x);
      o10 += ex*BLO(vc.y);  o11 += ex*BHI(vc.y);
    }
  }
  sum += __shfl_xor(sum, 1);
  o0 += __shfl_xor(o0,1);  o1 += __shfl_xor(o1,1);
  o2 += __shfl_xor(o2,1);  o3 += __shfl_xor(o3,1);
  o4 += __shfl_xor(o4,1);  o5 += __shfl_xor(o5,1);
  o6 += __shfl_xor(o6,1);  o7 += __shfl_xor(o7,1);
  o8 += __shfl_xor(o8,1);  o9 += __shfl_xor(o9,1);
  o10 += __shfl_xor(o10,1);o11 += __shfl_xor(o11,1);
  if (e == 0) {
    float inv = 1.f/sum;
    float* ap = aol + pixidx*CD + head*HDIM;
    ap[0]=o0*inv;  ap[1]=o1*inv;  ap[2]=o2*inv;  ap[3]=o3*inv;
    ap[4]=o4*inv;  ap[5]=o5*inv;  ap[6]=o6*inv;  ap[7]=o7*inv;
    ap[8]=o8*inv;  ap[9]=o9*inv;  ap[10]=o10*inv; ap[11]=o11*inv;
  }
  __syncthreads();
  const int c = lane;
  const int pg = wv;
  if (c < CD) {
    const float bias = bproj[c];
    const float* wrow = wpl + c*49;
    float acc[8];
#pragma unroll
    for (int r=0;r<8;r++) acc[r]=bias;
#pragma unroll 1
    for (int i0=0; i0<CD; i0+=4) {
      float w0=wrow[i0], w1=wrow[i0+1], w2=wrow[i0+2], w3=wrow[i0+3];
#pragma unroll
      for (int r=0;r<8;r++) {
        float4 a4 = *reinterpret_cast<const float4*>(&aol[(pg*8+r)*CD + i0]);  // broadcast
        acc[r] += a4.x*w0 + a4.y*w1 + a4.z*w2 + a4.w*w3;
      }
    }
#pragma unroll
    for (int r=0;r<8;r++) {
      int px = pg*8 + r;
      int tt = t0 + (px & 7), ww = w0 + (px >> 3);
      dst[((size_t)tt*PD + ww)*CD + c] = acc[r];
    }
  }
}

extern "C" void kernel_launch(void* const* d_in, const int* in_sizes, int n_in,
                              void* d_out, int out_size, void* d_ws, size_t ws_size,
                              hipStream_t stream) {
  (void)in_sizes; (void)n_in; (void)out_size; (void)ws_size;
  const float* x        = (const float*)d_in[0];
  const float* w_ih_l0  = (const float*)d_in[1];
  const float* w_hh_l0  = (const float*)d_in[2];
  const float* b_ih_l0  = (const float*)d_in[3];
  const float* b_hh_l0  = (const float*)d_in[4];
  const float* w_ih_l0r = (const float*)d_in[5];
  const float* w_hh_l0r = (const float*)d_in[6];
  const float* b_ih_l0r = (const float*)d_in[7];
  const float* b_hh_l0r = (const float*)d_in[8];
  const float* w_ih_l1  = (const float*)d_in[9];
  const float* w_hh_l1  = (const float*)d_in[10];
  const float* b_ih_l1  = (const float*)d_in[11];
  const float* b_hh_l1  = (const float*)d_in[12];
  const float* w_ih_l1r = (const float*)d_in[13];
  const float* w_hh_l1r = (const float*)d_in[14];
  const float* b_ih_l1r = (const float*)d_in[15];
  const float* b_hh_l1r = (const float*)d_in[16];
  const float* w_qkv    = (const float*)d_in[17];
  const float* b_qkv    = (const float*)d_in[18];
  const float* rpb      = (const float*)d_in[19];
  const float* w_proj   = (const float*)d_in[20];
  const float* b_proj   = (const float*)d_in[21];
  float* out = (float*)d_out;

  float* ws = (float*)d_ws;
  const size_t NPIX = (size_t)TD*PD;
  float* XG = ws;                              // [2][PD][TD][GD]
  float* H0 = XG + (size_t)2*PD*TD*GD;         // [PD*TD][CD]
  float* Y  = H0 + NPIX*CD;                    // [TD*PD][CD]
  float* Qb = Y  + NPIX*CD;
  unsigned short* Kb = (unsigned short*)(Qb + NPIX*CD);
  unsigned short* Vb = Kb + NPIX*64;

  xg0_kernel<<<dim3(256,2),192,0,stream>>>(x, w_ih_l0, w_ih_l0r, b_ih_l0, b_hh_l0, b_ih_l0r, b_hh_l0r, XG);
  lstm_kernel<<<22,512,0,stream>>>(XG, w_hh_l0, w_hh_l0r, H0, 0);
  xg1_kernel<<<352,192,0,stream>>>(H0, w_ih_l1, w_ih_l1r, b_ih_l1, b_hh_l1, b_ih_l1r, b_hh_l1r, XG);
  lstm_kernel<<<22,512,0,stream>>>(XG, w_hh_l1, w_hh_l1r, Y, 1);

  for (int l=0; l<2; ++l) {
    qkv_kernel<<<352,192,0,stream>>>(Y, w_qkv, b_qkv, Qb, Kb, Vb);
    natten_kernel<<<176,512,0,stream>>>(Qb, Kb, Vb, rpb, w_proj, b_proj, (l==1)? out : Y);
  }
}

// Round 17
// 228.449 us; speedup vs baseline: 1.0906x; 1.0906x over previous
//
#include <hip/hip_runtime.h>

#define PD 88      // sequences == W dim
#define TD 128     // time == T dim
#define I0 133     // layer0 input size
#define HID 24     // LSTM hidden
#define GD 96      // gates = 4*HID
#define CD 48      // channels = 2*HID
#define NH 4       // heads
#define HDIM 12    // head dim
#define KW 13      // neighborhood

typedef int int2v __attribute__((ext_vector_type(2)));

__device__ __forceinline__ int imin(int a,int b){return a<b?a:b;}
__device__ __forceinline__ int imax(int a,int b){return a>b?a:b;}

__device__ __forceinline__ float actg(float sa, float ss, float sb, float x) {
  return sa * __builtin_amdgcn_rcpf(1.f + __expf(-ss * x)) + sb;
}
// f32 -> bf16 RTNE
__device__ __forceinline__ unsigned short f2bf(float f) {
  unsigned u = __float_as_uint(f);
  u = u + 0x7fffu + ((u >> 16) & 1u);
  return (unsigned short)(u >> 16);
}
#define BLO(u) __uint_as_float((u) << 16)
#define BHI(u) __uint_as_float((u) & 0xffff0000u)

// ============ xg layer0 v6 (r13-proven) ============
__global__ __launch_bounds__(192) void xg0_kernel(
    const float* __restrict__ x,
    const float* __restrict__ wf, const float* __restrict__ wb,
    const float* __restrict__ bif, const float* __restrict__ bhf,
    const float* __restrict__ bib, const float* __restrict__ bhb,
    float* __restrict__ xg) {
  __shared__ __align__(16) float wl[GD*I0];     // 51.1 KB
  __shared__ __align__(16) float al[2][16*136]; // 17.4 KB -> 68.5 KB total
  const int dir = blockIdx.y;
  const int tid = threadIdx.x;
  const float* W = dir ? wb : wf;
  for (int idx = tid; idx < GD*I0/4; idx += 192)
    reinterpret_cast<float4*>(wl)[idx] = reinterpret_cast<const float4*>(W)[idx];
  const int c  = tid % GD;
  const int rg = tid / GD;
  const float bias = (dir ? (bib[c]+bhb[c]) : (bif[c]+bhf[c]));
  const float* wrow = wl + c*I0;
  {
    const int tile = blockIdx.x;
    const int p = tile >> 3, tc = tile & 7;
    for (int idx = tid; idx < 16*I0; idx += 192) {
      int r = idx / I0, i = idx - r*I0;
      al[0][r*136 + i] = x[((size_t)(tc*16+r)*PD + p)*I0 + i];
    }
  }
  __syncthreads();
  int buf = 0;
#pragma unroll 1
  for (int tile = blockIdx.x; tile < 704; tile += 256, buf ^= 1) {
    const int ntile = tile + 256;
    if (ntile < 704) {
      const int np = ntile >> 3, ntc = ntile & 7;
      for (int idx = tid; idx < 16*I0; idx += 192) {
        int r = idx / I0, i = idx - r*I0;
        al[buf^1][r*136 + i] = x[((size_t)(ntc*16+r)*PD + np)*I0 + i];
      }
    }
    const int p = tile >> 3, tc = tile & 7;
    float acc[8];
#pragma unroll
    for (int r=0;r<8;r++) acc[r]=bias;
    const float* ab = al[buf] + rg*8*136;
#pragma unroll 1
    for (int i0=0; i0<132; i0+=4) {
      float w0=wrow[i0], w1=wrow[i0+1], w2=wrow[i0+2], w3=wrow[i0+3];
#pragma unroll
      for (int r=0;r<8;r++) {
        float4 a4 = *reinterpret_cast<const float4*>(&ab[r*136 + i0]);  // broadcast
        acc[r] += a4.x*w0 + a4.y*w1 + a4.z*w2 + a4.w*w3;
      }
    }
    {
      float wlast = wrow[132];
#pragma unroll
      for (int r=0;r<8;r++) acc[r] += ab[r*136 + 132]*wlast;
    }
    float* op = xg + ((size_t)dir*PD*TD + (size_t)p*TD + tc*16 + rg*8)*GD + c;
#pragma unroll
    for (int r=0;r<8;r++) op[(size_t)r*GD] = acc[r];
    __syncthreads();
  }
}

// ============ LSTM recurrence (r14-proven: 2-gate/lane, permlane32_swap) ============
__device__ __forceinline__ void lstm_dir_run(
    const float* xlb, const float* __restrict__ wh,
    float* hout, ptrdiff_t hstep, int dirflag, int l) {
  const int j = l & 31;
  const bool hi = l >= 32;
  const int r1 = imin(hi ? 48+j : j,    95);
  const int r2 = imin(hi ? 72+j : 24+j, 95);
  float wv1[HID], wv2[HID];
#pragma unroll
  for (int k=0;k<HID;k+=4) {
    float4 a4 = *reinterpret_cast<const float4*>(wh + r1*HID + k);
    wv1[k]=a4.x; wv1[k+1]=a4.y; wv1[k+2]=a4.z; wv1[k+3]=a4.w;
    float4 b4 = *reinterpret_cast<const float4*>(wh + r2*HID + k);
    wv2[k]=b4.x; wv2[k+1]=b4.y; wv2[k+2]=b4.z; wv2[k+3]=b4.w;
  }
  const float sa1 = hi?2.f:1.f, ss1 = hi?2.f:1.f, sb1 = hi?-1.f:0.f;
  float h[HID];
#pragma unroll
  for (int k=0;k<HID;k++) h[k]=0.f;
  float c = 0.f;
  const int dt = dirflag ? -1 : 1;
  const float* xrow = xlb + (dirflag ? (TD-1)*GD : 0);
  const ptrdiff_t xstep = (ptrdiff_t)dt*GD;
  float x1 = xrow[r1];
  float x2 = xrow[r2];
#pragma unroll 4
  for (int s=0; s<TD; ++s) {
    float n1 = xrow[xstep + r1];
    float n2 = xrow[xstep + r2];
    float pa0=0.f,pa1=0.f,pa2=0.f,pa3=0.f, pb0=0.f,pb1=0.f,pb2=0.f,pb3=0.f;
#pragma unroll
    for (int k=0;k<HID;k+=4) {
      pa0 += wv1[k]  *h[k];   pb0 += wv2[k]  *h[k];
      pa1 += wv1[k+1]*h[k+1]; pb1 += wv2[k+1]*h[k+1];
      pa2 += wv1[k+2]*h[k+2]; pb2 += wv2[k+2]*h[k+2];
      pa3 += wv1[k+3]*h[k+3]; pb3 += wv2[k+3]*h[k+3];
    }
    float acc1 = x1 + ((pa0+pa1)+(pa2+pa3));
    float acc2 = x2 + ((pb0+pb1)+(pb2+pb3));
    float v1 = actg(sa1, ss1, sb1, acc1);
    float v2 = __builtin_amdgcn_rcpf(1.f + __expf(-acc2));
    int2v rg_ = __builtin_amdgcn_permlane32_swap(__float_as_int(v1), __float_as_int(v1), false, false);
    int2v ro_ = __builtin_amdgcn_permlane32_swap(__float_as_int(v2), __float_as_int(v2), false, false);
    float gg = __int_as_float(rg_.y);
    float oo = __int_as_float(ro_.y);
    c = v2*c + v1*gg;
    float th = 2.f*__builtin_amdgcn_rcpf(1.f + __expf(-2.f*c)) - 1.f;
    float hn = oo * th;
    if (l < HID) *hout = hn;
#pragma unroll
    for (int k=0;k<HID;k++)
      h[k] = __int_as_float(__builtin_amdgcn_readlane(__float_as_int(hn), k));
    hout += hstep; xrow += xstep;
    x1 = n1; x2 = n2;
  }
}

// ============ fused BiLSTM stack (r14-proven, 88.4 us) ============
__global__ __launch_bounds__(256) void bilstm_kernel(
    const float* __restrict__ xg,
    const float* __restrict__ wh0f, const float* __restrict__ wh0b,
    const float* __restrict__ wi1f, const float* __restrict__ wi1b,
    const float* __restrict__ bi1f, const float* __restrict__ bh1f,
    const float* __restrict__ bi1b, const float* __restrict__ bh1b,
    const float* __restrict__ wh1f, const float* __restrict__ wh1b,
    float* __restrict__ outY) {
  __shared__ __align__(16) float xl[2*TD*GD];   // 98304 B
  __shared__ __align__(16) float hb[TD*CD];     // 24576 B
  __shared__ float w1l[192*49];                 // 37632 B -> 160512 B
  const int p   = blockIdx.x;
  const int tid = threadIdx.x;
  const int wv  = tid >> 6;
  const int lane = tid & 63;
#pragma unroll 1
  for (int d = 0; d < 2; ++d) {
    const float* src = xg + ((size_t)d*PD + p)*TD*GD;
#pragma unroll 1
    for (int ch = 0; ch < 12; ++ch) {
      __builtin_amdgcn_global_load_lds(
        (const __attribute__((address_space(1))) unsigned*)(src + ch*1024 + tid*4),
        (__attribute__((address_space(3))) unsigned*)(&xl[d*TD*GD + ch*1024 + wv*256]),
        16, 0, 0);
    }
  }
  __syncthreads();
  if (wv < 2) {
    const int d = wv;
    float* h0 = hb + (d ? (TD-1)*CD : 0) + d*HID + lane;
    lstm_dir_run(xl + d*TD*GD, d ? wh0b : wh0f, h0,
                 (ptrdiff_t)(d ? -CD : CD), d, lane);
  } else {
    const int t2 = tid - 128;
    for (int idx = t2; idx < 192*CD; idx += 128) {
      int cc = idx / CD, i = idx - cc*CD;
      w1l[cc*49 + i] = (cc < GD) ? wi1f[cc*CD + i] : wi1b[(cc-GD)*CD + i];
    }
  }
  __syncthreads();
  if (tid < 192) {
    const int c = tid;
    const int d1 = c >= GD;
    const int g = c - d1*GD;
    const float bias = d1 ? (bi1b[g]+bh1b[g]) : (bi1f[g]+bh1f[g]);
    const float* wrow = w1l + c*49;
    float* xout = xl + d1*TD*GD + g;
#pragma unroll 1
    for (int rc = 0; rc < 4; ++rc) {
      float acc[32];
#pragma unroll
      for (int r=0;r<32;r++) acc[r]=bias;
      const float* ab = hb + rc*32*CD;
#pragma unroll 1
      for (int i0=0; i0<CD; i0+=4) {
        float w0=wrow[i0], w1=wrow[i0+1], w2=wrow[i0+2], w3=wrow[i0+3];
#pragma unroll
        for (int r=0;r<32;r++) {
          float4 a4 = *reinterpret_cast<const float4*>(&ab[r*CD + i0]);  // broadcast
          acc[r] += a4.x*w0 + a4.y*w1 + a4.z*w2 + a4.w*w3;
        }
      }
#pragma unroll
      for (int r=0;r<32;r++) xout[(size_t)(rc*32+r)*GD] = acc[r];
    }
  }
  __syncthreads();
  if (wv < 2) {
    const int d = wv;
    float* y0 = outY + ((size_t)(d ? TD-1 : 0)*PD + p)*CD + d*HID + lane;
    lstm_dir_run(xl + d*TD*GD, d ? wh1b : wh1f, y0,
                 (ptrdiff_t)(d ? -(ptrdiff_t)PD*CD : (ptrdiff_t)PD*CD), d, lane);
  }
}

// ============ qkv projection (r8-proven) ============
__global__ __launch_bounds__(192) void qkv_kernel(
    const float* __restrict__ y, const float* __restrict__ wq,
    const float* __restrict__ bq,
    float* __restrict__ Qb, unsigned short* __restrict__ Kb,
    unsigned short* __restrict__ Vb) {
  __shared__ float wl[144*53];
  __shared__ __align__(16) float al[32*CD];
  for (int idx = threadIdx.x; idx < 144*CD; idx += 192) {
    int cc = idx / CD, i = idx - cc*CD;
    wl[cc*53 + i] = wq[idx];
  }
  const int r0 = blockIdx.x * 32;
  for (int idx = threadIdx.x; idx < 32*CD/4; idx += 192)
    reinterpret_cast<float4*>(al)[idx] =
        reinterpret_cast<const float4*>(y + (size_t)r0*CD)[idx];
  __syncthreads();
  const int c = threadIdx.x;
  if (c >= 144) return;
  const float bias = bq[c];
  const float* wrow = wl + c*53;
  float acc[32];
#pragma unroll
  for (int r=0;r<32;r++) acc[r]=bias;
#pragma unroll 1
  for (int i0=0; i0<CD; i0+=4) {
    float w0=wrow[i0], w1=wrow[i0+1], w2=wrow[i0+2], w3=wrow[i0+3];
#pragma unroll
    for (int r=0;r<32;r++) {
      float4 a4 = *reinterpret_cast<const float4*>(&al[r*CD + i0]);
      acc[r] += a4.x*w0 + a4.y*w1 + a4.z*w2 + a4.w*w3;
    }
  }
  if (c < CD) {
#pragma unroll
    for (int r=0;r<32;r++)
      Qb[(size_t)(r0+r)*CD + c] = acc[r]*0.28867513459481287f;
  } else if (c < 2*CD) {
    int cc = c - CD, head = cc / HDIM, jj = cc - head*HDIM;
#pragma unroll
    for (int r=0;r<32;r++)
      Kb[(size_t)(r0+r)*64 + head*16 + jj] = f2bf(acc[r]);
  } else {
    int cc = c - 2*CD, head = cc / HDIM, jj = cc - head*HDIM;
#pragma unroll
    for (int r=0;r<32;r++)
      Vb[(size_t)(r0+r)*64 + head*16 + jj] = f2bf(acc[r]);
  }
}

// ============ NATTEN 2D + fused proj: 1-deep software-pipelined neighbor loop ============
// Flattened 91 iters (13pp x 7q); iteration i+1's 7 LDS loads issued before
// iteration i's compute -> LDS latency hidden under ~100cyc of VALU.
__global__ __launch_bounds__(512) void natten_kernel(
    const float* __restrict__ Qb, const unsigned short* __restrict__ Kb,
    const unsigned short* __restrict__ Vb, const float* __restrict__ rpb,
    const float* __restrict__ wproj, const float* __restrict__ bproj,
    float* __restrict__ dst) {
  __shared__ __align__(8) unsigned kl[NH*400*6];   // 38.4 KB
  __shared__ __align__(8) unsigned vl[NH*400*6];   // 38.4 KB
  __shared__ unsigned short bl[NH*625];            // 5 KB
  __shared__ __align__(16) float aol[64*CD];       // 12.3 KB
  __shared__ float wpl[CD*49];                     // 9.4 KB -> 103.5 KB
  const int tb = blockIdx.x & 15;
  const int wb = blockIdx.x >> 4;
  const int t0 = tb*8, w0 = wb*8;
  const int ht0 = imin(imax(t0-6,0), TD-KW);
  const int hw0 = imin(imax(w0-6,0), PD-KW);
  for (int idx = threadIdx.x; idx < NH*625; idx += 512) bl[idx] = f2bf(rpb[idx]);
  for (int idx = threadIdx.x; idx < CD*CD; idx += 512) {
    int cc = idx / CD, i = idx - cc*CD;
    wpl[cc*49 + i] = wproj[idx];
  }
  for (int idx = threadIdx.x; idx < NH*400; idx += 512) {
    int h = idx / 400, pos = idx - h*400;
    int lw = pos / 20, lt = pos - lw*20;
    int gt = imin(ht0+lt, TD-1), gw = imin(hw0+lw, PD-1);
    size_t gb = ((size_t)gt*PD + gw)*64 + h*16;
    const uint2* kg = reinterpret_cast<const uint2*>(Kb + gb);
    const uint2* vg = reinterpret_cast<const uint2*>(Vb + gb);
    unsigned* kd = kl + idx*6;
    unsigned* vd = vl + idx*6;
    *reinterpret_cast<uint2*>(kd)   = kg[0];
    *reinterpret_cast<uint2*>(kd+2) = kg[1];
    *reinterpret_cast<uint2*>(kd+4) = kg[2];
    *reinterpret_cast<uint2*>(vd)   = vg[0];
    *reinterpret_cast<uint2*>(vd+2) = vg[1];
    *reinterpret_cast<uint2*>(vd+4) = vg[2];
  }
  __syncthreads();
  const int wv   = threadIdx.x >> 6;
  const int head = wv >> 1;
  const int lane = threadIdx.x & 63;
  const int e    = lane & 1;
  const int pixidx = (wv & 1)*32 + (lane >> 1);
  const int pt = pixidx & 7, pw = pixidx >> 3;   // pt-fast
  const int t = t0+pt, w = w0+pw;
  const int ts  = imin(imax(t-6,0), TD-KW);
  const int wsb = imin(imax(w-6,0), PD-KW);
  const int lt0 = ts - ht0, lw0 = wsb - hw0;
  const float* qp = Qb + ((size_t)t*PD + w)*CD + head*HDIM;
  float4 q0 = *reinterpret_cast<const float4*>(qp);
  float4 q1 = *reinterpret_cast<const float4*>(qp+4);
  float4 q2 = *reinterpret_cast<const float4*>(qp+8);
  const unsigned* kbp = kl + head*2400;
  const unsigned* vbp = vl + head*2400;
  const unsigned short* bb = bl + head*625 + (ts-t+12)*25 + (wsb-w+12);
  float sum=0.f;
  float o0=0,o1=0,o2=0,o3=0,o4=0,o5=0,o6=0,o7=0,o8=0,o9=0,o10=0,o11=0;
  // ---- software-pipelined flat loop: it = pp*7 + q7, qq = e + 2*q7 (clamped+masked) ----
  int pp = 0, q7 = 0;
  uint2 cka, ckb, ckc, cva, cvb, cvc;
  float cbias, cm;
  {
    const int qq = e;                       // it=0: always valid (e<=1<13)
    const int pos = (lw0+qq)*20 + lt0;
    const unsigned* kr = kbp + pos*6;
    const unsigned* vr = vbp + pos*6;
    cka=*reinterpret_cast<const uint2*>(kr);   ckb=*reinterpret_cast<const uint2*>(kr+2);
    ckc=*reinterpret_cast<const uint2*>(kr+4);
    cva=*reinterpret_cast<const uint2*>(vr);   cvb=*reinterpret_cast<const uint2*>(vr+2);
    cvc=*reinterpret_cast<const uint2*>(vr+4);
    cbias = BLO((unsigned)bb[qq]);
    cm = 1.f;
  }
#pragma unroll 1
  for (int it = 0; it < 91; ++it) {
    // issue next iteration's loads first (1-deep pipeline)
    int nq7 = q7 + 1, npp = pp;
    if (nq7 == 7) { nq7 = 0; npp = pp + 1; }
    uint2 nka, nkb, nkc, nva, nvb, nvc;
    float nbias = 0.f, nm = 0.f;
    if (it < 90) {
      const int nqq = e + 2*nq7;
      const int nqc = imin(nqq, 12);
      const int npos = (lw0+nqc)*20 + lt0 + npp;
      const unsigned* nkr = kbp + npos*6;
      const unsigned* nvr = vbp + npos*6;
      nka=*reinterpret_cast<const uint2*>(nkr);   nkb=*reinterpret_cast<const uint2*>(nkr+2);
      nkc=*reinterpret_cast<const uint2*>(nkr+4);
      nva=*reinterpret_cast<const uint2*>(nvr);   nvb=*reinterpret_cast<const uint2*>(nvr+2);
      nvc=*reinterpret_cast<const uint2*>(nvr+4);
      nbias = BLO((unsigned)bb[npp*25 + nqc]);
      nm = (nqq <= 12) ? 1.f : 0.f;
    }
    // compute with current registers
    float lg = cbias;
    lg += q0.x*BLO(cka.x) + q0.y*BHI(cka.x)
        + q0.z*BLO(cka.y) + q0.w*BHI(cka.y)
        + q1.x*BLO(ckb.x) + q1.y*BHI(ckb.x)
        + q1.z*BLO(ckb.y) + q1.w*BHI(ckb.y)
        + q2.x*BLO(ckc.x) + q2.y*BHI(ckc.x)
        + q2.z*BLO(ckc.y) + q2.w*BHI(ckc.y);
    float ex = cm * __expf(lg);
    sum += ex;
    o0  += ex*BLO(cva.x);  o1  += ex*BHI(cva.x);
    o2  += ex*BLO(cva.y);  o3  += ex*BHI(cva.y);
    o4  += ex*BLO(cvb.x);  o5  += ex*BHI(cvb.x);
    o6  += ex*BLO(cvb.y);  o7  += ex*BHI(cvb.y);
    o8  += ex*BLO(cvc.x);  o9  += ex*BHI(cvc.x);
    o10 += ex*BLO(cvc.y);  o11 += ex*BHI(cvc.y);
    // rotate
    cka=nka; ckb=nkb; ckc=nkc; cva=nva; cvb=nvb; cvc=nvc;
    cbias=nbias; cm=nm; pp=npp; q7=nq7;
  }
  sum += __shfl_xor(sum, 1);
  o0 += __shfl_xor(o0,1);  o1 += __shfl_xor(o1,1);
  o2 += __shfl_xor(o2,1);  o3 += __shfl_xor(o3,1);
  o4 += __shfl_xor(o4,1);  o5 += __shfl_xor(o5,1);
  o6 += __shfl_xor(o6,1);  o7 += __shfl_xor(o7,1);
  o8 += __shfl_xor(o8,1);  o9 += __shfl_xor(o9,1);
  o10 += __shfl_xor(o10,1);o11 += __shfl_xor(o11,1);
  if (e == 0) {
    float inv = 1.f/sum;
    float* ap = aol + pixidx*CD + head*HDIM;
    ap[0]=o0*inv;  ap[1]=o1*inv;  ap[2]=o2*inv;  ap[3]=o3*inv;
    ap[4]=o4*inv;  ap[5]=o5*inv;  ap[6]=o6*inv;  ap[7]=o7*inv;
    ap[8]=o8*inv;  ap[9]=o9*inv;  ap[10]=o10*inv; ap[11]=o11*inv;
  }
  __syncthreads();
  const int c = lane;
  const int pg = wv;
  if (c < CD) {
    const float bias = bproj[c];
    const float* wrow = wpl + c*49;
    float acc[8];
#pragma unroll
    for (int r=0;r<8;r++) acc[r]=bias;
#pragma unroll 1
    for (int i0=0; i0<CD; i0+=4) {
      float w0=wrow[i0], w1=wrow[i0+1], w2=wrow[i0+2], w3=wrow[i0+3];
#pragma unroll
      for (int r=0;r<8;r++) {
        float4 a4 = *reinterpret_cast<const float4*>(&aol[(pg*8+r)*CD + i0]);  // broadcast
        acc[r] += a4.x*w0 + a4.y*w1 + a4.z*w2 + a4.w*w3;
      }
    }
#pragma unroll
    for (int r=0;r<8;r++) {
      int px = pg*8 + r;
      int tt = t0 + (px & 7), ww = w0 + (px >> 3);
      dst[((size_t)tt*PD + ww)*CD + c] = acc[r];
    }
  }
}

extern "C" void kernel_launch(void* const* d_in, const int* in_sizes, int n_in,
                              void* d_out, int out_size, void* d_ws, size_t ws_size,
                              hipStream_t stream) {
  (void)in_sizes; (void)n_in; (void)out_size; (void)ws_size;
  const float* x        = (const float*)d_in[0];
  const float* w_ih_l0  = (const float*)d_in[1];
  const float* w_hh_l0  = (const float*)d_in[2];
  const float* b_ih_l0  = (const float*)d_in[3];
  const float* b_hh_l0  = (const float*)d_in[4];
  const float* w_ih_l0r = (const float*)d_in[5];
  const float* w_hh_l0r = (const float*)d_in[6];
  const float* b_ih_l0r = (const float*)d_in[7];
  const float* b_hh_l0r = (const float*)d_in[8];
  const float* w_ih_l1  = (const float*)d_in[9];
  const float* w_hh_l1  = (const float*)d_in[10];
  const float* b_ih_l1  = (const float*)d_in[11];
  const float* b_hh_l1  = (const float*)d_in[12];
  const float* w_ih_l1r = (const float*)d_in[13];
  const float* w_hh_l1r = (const float*)d_in[14];
  const float* b_ih_l1r = (const float*)d_in[15];
  const float* b_hh_l1r = (const float*)d_in[16];
  const float* w_qkv    = (const float*)d_in[17];
  const float* b_qkv    = (const float*)d_in[18];
  const float* rpb      = (const float*)d_in[19];
  const float* w_proj   = (const float*)d_in[20];
  const float* b_proj   = (const float*)d_in[21];
  float* out = (float*)d_out;

  float* ws = (float*)d_ws;
  const size_t NPIX = (size_t)TD*PD;
  float* XG = ws;
  float* Y  = XG + (size_t)2*PD*TD*GD;
  float* Qb = Y  + NPIX*CD;
  unsigned short* Kb = (unsigned short*)(Qb + NPIX*CD);
  unsigned short* Vb = Kb + NPIX*64;

  xg0_kernel<<<dim3(256,2),192,0,stream>>>(x, w_ih_l0, w_ih_l0r, b_ih_l0, b_hh_l0, b_ih_l0r, b_hh_l0r, XG);
  bilstm_kernel<<<PD,256,0,stream>>>(XG, w_hh_l0, w_hh_l0r,
                                     w_ih_l1, w_ih_l1r,
                                     b_ih_l1, b_hh_l1, b_ih_l1r, b_hh_l1r,
                                     w_hh_l1, w_hh_l1r, Y);

  for (int l=0; l<2; ++l) {
    qkv_kernel<<<352,192,0,stream>>>(Y, w_qkv, b_qkv, Qb, Kb, Vb);
    natten_kernel<<<176,512,0,stream>>>(Qb, Kb, Vb, rpb, w_proj, b_proj, (l==1)? out : Y);
  }
}

// Round 18
// 218.221 us; speedup vs baseline: 1.1417x; 1.0469x over previous
//
#include <hip/hip_runtime.h>

#define PD 88      // sequences == W dim
#define TD 128     // time == T dim
#define I0 133     // layer0 input size
#define HID 24     // LSTM hidden
#define GD 96      // gates = 4*HID
#define CD 48      // channels = 2*HID
#define NH 4       // heads
#define HDIM 12    // head dim
#define KW 13      // neighborhood

typedef int int2v __attribute__((ext_vector_type(2)));

__device__ __forceinline__ int imin(int a,int b){return a<b?a:b;}
__device__ __forceinline__ int imax(int a,int b){return a>b?a:b;}

__device__ __forceinline__ float actg(float sa, float ss, float sb, float x) {
  return sa * __builtin_amdgcn_rcpf(1.f + __expf(-ss * x)) + sb;
}
// f32 -> bf16 RTNE
__device__ __forceinline__ unsigned short f2bf(float f) {
  unsigned u = __float_as_uint(f);
  u = u + 0x7fffu + ((u >> 16) & 1u);
  return (unsigned short)(u >> 16);
}
#define BLO(u) __uint_as_float((u) << 16)
#define BHI(u) __uint_as_float((u) & 0xffff0000u)

// ============ xg layer0 v7: v6 grid-stride + 1-chunk-deep register prefetch ============
__global__ __launch_bounds__(192) void xg0_kernel(
    const float* __restrict__ x,
    const float* __restrict__ wf, const float* __restrict__ wb,
    const float* __restrict__ bif, const float* __restrict__ bhf,
    const float* __restrict__ bib, const float* __restrict__ bhb,
    float* __restrict__ xg) {
  __shared__ __align__(16) float wl[GD*I0];     // 51.1 KB
  __shared__ __align__(16) float al[2][16*136]; // 17.4 KB -> 68.5 KB total
  const int dir = blockIdx.y;
  const int tid = threadIdx.x;
  const float* W = dir ? wb : wf;
  for (int idx = tid; idx < GD*I0/4; idx += 192)
    reinterpret_cast<float4*>(wl)[idx] = reinterpret_cast<const float4*>(W)[idx];
  const int c  = tid % GD;
  const int rg = tid / GD;
  const float bias = (dir ? (bib[c]+bhb[c]) : (bif[c]+bhf[c]));
  const float* wrow = wl + c*I0;
  {
    const int tile = blockIdx.x;
    const int p = tile >> 3, tc = tile & 7;
    for (int idx = tid; idx < 16*I0; idx += 192) {
      int r = idx / I0, i = idx - r*I0;
      al[0][r*136 + i] = x[((size_t)(tc*16+r)*PD + p)*I0 + i];
    }
  }
  __syncthreads();
  int buf = 0;
#pragma unroll 1
  for (int tile = blockIdx.x; tile < 704; tile += 256, buf ^= 1) {
    const int ntile = tile + 256;
    if (ntile < 704) {
      const int np = ntile >> 3, ntc = ntile & 7;
      for (int idx = tid; idx < 16*I0; idx += 192) {
        int r = idx / I0, i = idx - r*I0;
        al[buf^1][r*136 + i] = x[((size_t)(ntc*16+r)*PD + np)*I0 + i];
      }
    }
    const int p = tile >> 3, tc = tile & 7;
    float acc[8];
#pragma unroll
    for (int r=0;r<8;r++) acc[r]=bias;
    const float* ab = al[buf] + rg*8*136;
    // 1-deep k-chunk software pipeline: prefetch chunk i+1's 8 broadcast b128s
    float4 cur0,cur1,cur2,cur3,cur4,cur5,cur6,cur7;
    cur0 = *reinterpret_cast<const float4*>(&ab[0*136]);
    cur1 = *reinterpret_cast<const float4*>(&ab[1*136]);
    cur2 = *reinterpret_cast<const float4*>(&ab[2*136]);
    cur3 = *reinterpret_cast<const float4*>(&ab[3*136]);
    cur4 = *reinterpret_cast<const float4*>(&ab[4*136]);
    cur5 = *reinterpret_cast<const float4*>(&ab[5*136]);
    cur6 = *reinterpret_cast<const float4*>(&ab[6*136]);
    cur7 = *reinterpret_cast<const float4*>(&ab[7*136]);
#pragma unroll 1
    for (int i0=0; i0<132; i0+=4) {
      const int ni = (i0+4 < 132) ? (i0+4) : i0;
      float4 nx0 = *reinterpret_cast<const float4*>(&ab[0*136 + ni]);
      float4 nx1 = *reinterpret_cast<const float4*>(&ab[1*136 + ni]);
      float4 nx2 = *reinterpret_cast<const float4*>(&ab[2*136 + ni]);
      float4 nx3 = *reinterpret_cast<const float4*>(&ab[3*136 + ni]);
      float4 nx4 = *reinterpret_cast<const float4*>(&ab[4*136 + ni]);
      float4 nx5 = *reinterpret_cast<const float4*>(&ab[5*136 + ni]);
      float4 nx6 = *reinterpret_cast<const float4*>(&ab[6*136 + ni]);
      float4 nx7 = *reinterpret_cast<const float4*>(&ab[7*136 + ni]);
      float w0=wrow[i0], w1=wrow[i0+1], w2=wrow[i0+2], w3=wrow[i0+3];
      acc[0] += cur0.x*w0 + cur0.y*w1 + cur0.z*w2 + cur0.w*w3;
      acc[1] += cur1.x*w0 + cur1.y*w1 + cur1.z*w2 + cur1.w*w3;
      acc[2] += cur2.x*w0 + cur2.y*w1 + cur2.z*w2 + cur2.w*w3;
      acc[3] += cur3.x*w0 + cur3.y*w1 + cur3.z*w2 + cur3.w*w3;
      acc[4] += cur4.x*w0 + cur4.y*w1 + cur4.z*w2 + cur4.w*w3;
      acc[5] += cur5.x*w0 + cur5.y*w1 + cur5.z*w2 + cur5.w*w3;
      acc[6] += cur6.x*w0 + cur6.y*w1 + cur6.z*w2 + cur6.w*w3;
      acc[7] += cur7.x*w0 + cur7.y*w1 + cur7.z*w2 + cur7.w*w3;
      cur0=nx0; cur1=nx1; cur2=nx2; cur3=nx3;
      cur4=nx4; cur5=nx5; cur6=nx6; cur7=nx7;
    }
    {
      float wlast = wrow[132];
#pragma unroll
      for (int r=0;r<8;r++) acc[r] += ab[r*136 + 132]*wlast;
    }
    float* op = xg + ((size_t)dir*PD*TD + (size_t)p*TD + tc*16 + rg*8)*GD + c;
#pragma unroll
    for (int r=0;r<8;r++) op[(size_t)r*GD] = acc[r];
    __syncthreads();
  }
}

// ============ LSTM recurrence (r14-proven: 2-gate/lane, permlane32_swap) ============
__device__ __forceinline__ void lstm_dir_run(
    const float* xlb, const float* __restrict__ wh,
    float* hout, ptrdiff_t hstep, int dirflag, int l) {
  const int j = l & 31;
  const bool hi = l >= 32;
  const int r1 = imin(hi ? 48+j : j,    95);
  const int r2 = imin(hi ? 72+j : 24+j, 95);
  float wv1[HID], wv2[HID];
#pragma unroll
  for (int k=0;k<HID;k+=4) {
    float4 a4 = *reinterpret_cast<const float4*>(wh + r1*HID + k);
    wv1[k]=a4.x; wv1[k+1]=a4.y; wv1[k+2]=a4.z; wv1[k+3]=a4.w;
    float4 b4 = *reinterpret_cast<const float4*>(wh + r2*HID + k);
    wv2[k]=b4.x; wv2[k+1]=b4.y; wv2[k+2]=b4.z; wv2[k+3]=b4.w;
  }
  const float sa1 = hi?2.f:1.f, ss1 = hi?2.f:1.f, sb1 = hi?-1.f:0.f;
  float h[HID];
#pragma unroll
  for (int k=0;k<HID;k++) h[k]=0.f;
  float c = 0.f;
  const int dt = dirflag ? -1 : 1;
  const float* xrow = xlb + (dirflag ? (TD-1)*GD : 0);
  const ptrdiff_t xstep = (ptrdiff_t)dt*GD;
  float x1 = xrow[r1];
  float x2 = xrow[r2];
#pragma unroll 4
  for (int s=0; s<TD; ++s) {
    float n1 = xrow[xstep + r1];
    float n2 = xrow[xstep + r2];
    float pa0=0.f,pa1=0.f,pa2=0.f,pa3=0.f, pb0=0.f,pb1=0.f,pb2=0.f,pb3=0.f;
#pragma unroll
    for (int k=0;k<HID;k+=4) {
      pa0 += wv1[k]  *h[k];   pb0 += wv2[k]  *h[k];
      pa1 += wv1[k+1]*h[k+1]; pb1 += wv2[k+1]*h[k+1];
      pa2 += wv1[k+2]*h[k+2]; pb2 += wv2[k+2]*h[k+2];
      pa3 += wv1[k+3]*h[k+3]; pb3 += wv2[k+3]*h[k+3];
    }
    float acc1 = x1 + ((pa0+pa1)+(pa2+pa3));
    float acc2 = x2 + ((pb0+pb1)+(pb2+pb3));
    float v1 = actg(sa1, ss1, sb1, acc1);
    float v2 = __builtin_amdgcn_rcpf(1.f + __expf(-acc2));
    int2v rg_ = __builtin_amdgcn_permlane32_swap(__float_as_int(v1), __float_as_int(v1), false, false);
    int2v ro_ = __builtin_amdgcn_permlane32_swap(__float_as_int(v2), __float_as_int(v2), false, false);
    float gg = __int_as_float(rg_.y);
    float oo = __int_as_float(ro_.y);
    c = v2*c + v1*gg;
    float th = 2.f*__builtin_amdgcn_rcpf(1.f + __expf(-2.f*c)) - 1.f;
    float hn = oo * th;
    if (l < HID) *hout = hn;
#pragma unroll
    for (int k=0;k<HID;k++)
      h[k] = __int_as_float(__builtin_amdgcn_readlane(__float_as_int(hn), k));
    hout += hstep; xrow += xstep;
    x1 = n1; x2 = n2;
  }
}

// ============ fused BiLSTM stack (r14-proven, 88.4 us) ============
__global__ __launch_bounds__(256) void bilstm_kernel(
    const float* __restrict__ xg,
    const float* __restrict__ wh0f, const float* __restrict__ wh0b,
    const float* __restrict__ wi1f, const float* __restrict__ wi1b,
    const float* __restrict__ bi1f, const float* __restrict__ bh1f,
    const float* __restrict__ bi1b, const float* __restrict__ bh1b,
    const float* __restrict__ wh1f, const float* __restrict__ wh1b,
    float* __restrict__ outY) {
  __shared__ __align__(16) float xl[2*TD*GD];   // 98304 B
  __shared__ __align__(16) float hb[TD*CD];     // 24576 B
  __shared__ float w1l[192*49];                 // 37632 B -> 160512 B
  const int p   = blockIdx.x;
  const int tid = threadIdx.x;
  const int wv  = tid >> 6;
  const int lane = tid & 63;
#pragma unroll 1
  for (int d = 0; d < 2; ++d) {
    const float* src = xg + ((size_t)d*PD + p)*TD*GD;
#pragma unroll 1
    for (int ch = 0; ch < 12; ++ch) {
      __builtin_amdgcn_global_load_lds(
        (const __attribute__((address_space(1))) unsigned*)(src + ch*1024 + tid*4),
        (__attribute__((address_space(3))) unsigned*)(&xl[d*TD*GD + ch*1024 + wv*256]),
        16, 0, 0);
    }
  }
  __syncthreads();
  if (wv < 2) {
    const int d = wv;
    float* h0 = hb + (d ? (TD-1)*CD : 0) + d*HID + lane;
    lstm_dir_run(xl + d*TD*GD, d ? wh0b : wh0f, h0,
                 (ptrdiff_t)(d ? -CD : CD), d, lane);
  } else {
    const int t2 = tid - 128;
    for (int idx = t2; idx < 192*CD; idx += 128) {
      int cc = idx / CD, i = idx - cc*CD;
      w1l[cc*49 + i] = (cc < GD) ? wi1f[cc*CD + i] : wi1b[(cc-GD)*CD + i];
    }
  }
  __syncthreads();
  if (tid < 192) {
    const int c = tid;
    const int d1 = c >= GD;
    const int g = c - d1*GD;
    const float bias = d1 ? (bi1b[g]+bh1b[g]) : (bi1f[g]+bh1f[g]);
    const float* wrow = w1l + c*49;
    float* xout = xl + d1*TD*GD + g;
#pragma unroll 1
    for (int rc = 0; rc < 4; ++rc) {
      float acc[32];
#pragma unroll
      for (int r=0;r<32;r++) acc[r]=bias;
      const float* ab = hb + rc*32*CD;
#pragma unroll 1
      for (int i0=0; i0<CD; i0+=4) {
        float w0=wrow[i0], w1=wrow[i0+1], w2=wrow[i0+2], w3=wrow[i0+3];
#pragma unroll
        for (int r=0;r<32;r++) {
          float4 a4 = *reinterpret_cast<const float4*>(&ab[r*CD + i0]);  // broadcast
          acc[r] += a4.x*w0 + a4.y*w1 + a4.z*w2 + a4.w*w3;
        }
      }
#pragma unroll
      for (int r=0;r<32;r++) xout[(size_t)(rc*32+r)*GD] = acc[r];
    }
  }
  __syncthreads();
  if (wv < 2) {
    const int d = wv;
    float* y0 = outY + ((size_t)(d ? TD-1 : 0)*PD + p)*CD + d*HID + lane;
    lstm_dir_run(xl + d*TD*GD, d ? wh1b : wh1f, y0,
                 (ptrdiff_t)(d ? -(ptrdiff_t)PD*CD : (ptrdiff_t)PD*CD), d, lane);
  }
}

// ============ qkv projection (r8-proven) ============
__global__ __launch_bounds__(192) void qkv_kernel(
    const float* __restrict__ y, const float* __restrict__ wq,
    const float* __restrict__ bq,
    float* __restrict__ Qb, unsigned short* __restrict__ Kb,
    unsigned short* __restrict__ Vb) {
  __shared__ float wl[144*53];
  __shared__ __align__(16) float al[32*CD];
  for (int idx = threadIdx.x; idx < 144*CD; idx += 192) {
    int cc = idx / CD, i = idx - cc*CD;
    wl[cc*53 + i] = wq[idx];
  }
  const int r0 = blockIdx.x * 32;
  for (int idx = threadIdx.x; idx < 32*CD/4; idx += 192)
    reinterpret_cast<float4*>(al)[idx] =
        reinterpret_cast<const float4*>(y + (size_t)r0*CD)[idx];
  __syncthreads();
  const int c = threadIdx.x;
  if (c >= 144) return;
  const float bias = bq[c];
  const float* wrow = wl + c*53;
  float acc[32];
#pragma unroll
  for (int r=0;r<32;r++) acc[r]=bias;
#pragma unroll 1
  for (int i0=0; i0<CD; i0+=4) {
    float w0=wrow[i0], w1=wrow[i0+1], w2=wrow[i0+2], w3=wrow[i0+3];
#pragma unroll
    for (int r=0;r<32;r++) {
      float4 a4 = *reinterpret_cast<const float4*>(&al[r*CD + i0]);
      acc[r] += a4.x*w0 + a4.y*w1 + a4.z*w2 + a4.w*w3;
    }
  }
  if (c < CD) {
#pragma unroll
    for (int r=0;r<32;r++)
      Qb[(size_t)(r0+r)*CD + c] = acc[r]*0.28867513459481287f;
  } else if (c < 2*CD) {
    int cc = c - CD, head = cc / HDIM, jj = cc - head*HDIM;
#pragma unroll
    for (int r=0;r<32;r++)
      Kb[(size_t)(r0+r)*64 + head*16 + jj] = f2bf(acc[r]);
  } else {
    int cc = c - 2*CD, head = cc / HDIM, jj = cc - head*HDIM;
#pragma unroll
    for (int r=0;r<32;r++)
      Vb[(size_t)(r0+r)*64 + head*16 + jj] = f2bf(acc[r]);
  }
}

// ============ NATTEN 2D + fused proj (r14-proven: 24B rows, pair split, unroll 2) ============
__global__ __launch_bounds__(512) void natten_kernel(
    const float* __restrict__ Qb, const unsigned short* __restrict__ Kb,
    const unsigned short* __restrict__ Vb, const float* __restrict__ rpb,
    const float* __restrict__ wproj, const float* __restrict__ bproj,
    float* __restrict__ dst) {
  __shared__ __align__(8) unsigned kl[NH*400*6];   // 38.4 KB
  __shared__ __align__(8) unsigned vl[NH*400*6];   // 38.4 KB
  __shared__ unsigned short bl[NH*625];            // 5 KB
  __shared__ __align__(16) float aol[64*CD];       // 12.3 KB
  __shared__ float wpl[CD*49];                     // 9.4 KB -> 103.5 KB
  const int tb = blockIdx.x & 15;
  const int wb = blockIdx.x >> 4;
  const int t0 = tb*8, w0 = wb*8;
  const int ht0 = imin(imax(t0-6,0), TD-KW);
  const int hw0 = imin(imax(w0-6,0), PD-KW);
  for (int idx = threadIdx.x; idx < NH*625; idx += 512) bl[idx] = f2bf(rpb[idx]);
  for (int idx = threadIdx.x; idx < CD*CD; idx += 512) {
    int cc = idx / CD, i = idx - cc*CD;
    wpl[cc*49 + i] = wproj[idx];
  }
  for (int idx = threadIdx.x; idx < NH*400; idx += 512) {
    int h = idx / 400, pos = idx - h*400;
    int lw = pos / 20, lt = pos - lw*20;
    int gt = imin(ht0+lt, TD-1), gw = imin(hw0+lw, PD-1);
    size_t gb = ((size_t)gt*PD + gw)*64 + h*16;
    const uint2* kg = reinterpret_cast<const uint2*>(Kb + gb);
    const uint2* vg = reinterpret_cast<const uint2*>(Vb + gb);
    unsigned* kd = kl + idx*6;
    unsigned* vd = vl + idx*6;
    *reinterpret_cast<uint2*>(kd)   = kg[0];
    *reinterpret_cast<uint2*>(kd+2) = kg[1];
    *reinterpret_cast<uint2*>(kd+4) = kg[2];
    *reinterpret_cast<uint2*>(vd)   = vg[0];
    *reinterpret_cast<uint2*>(vd+2) = vg[1];
    *reinterpret_cast<uint2*>(vd+4) = vg[2];
  }
  __syncthreads();
  const int wv   = threadIdx.x >> 6;
  const int head = wv >> 1;
  const int lane = threadIdx.x & 63;
  const int e    = lane & 1;
  const int pixidx = (wv & 1)*32 + (lane >> 1);
  const int pt = pixidx & 7, pw = pixidx >> 3;   // pt-fast
  const int t = t0+pt, w = w0+pw;
  const int ts  = imin(imax(t-6,0), TD-KW);
  const int wsb = imin(imax(w-6,0), PD-KW);
  const int lt0 = ts - ht0, lw0 = wsb - hw0;
  const float* qp = Qb + ((size_t)t*PD + w)*CD + head*HDIM;
  float4 q0 = *reinterpret_cast<const float4*>(qp);
  float4 q1 = *reinterpret_cast<const float4*>(qp+4);
  float4 q2 = *reinterpret_cast<const float4*>(qp+8);
  const unsigned* kbp = kl + head*2400;
  const unsigned* vbp = vl + head*2400;
  const unsigned short* bb = bl + head*625 + (ts-t+12)*25 + (wsb-w+12);
  float sum=0.f;
  float o0=0,o1=0,o2=0,o3=0,o4=0,o5=0,o6=0,o7=0,o8=0,o9=0,o10=0,o11=0;
  for (int pp=0; pp<KW; ++pp) {
    const int ltp = lt0+pp;
    const unsigned short* br = bb + pp*25;
#pragma unroll 2
    for (int qq=e; qq<KW; qq+=2) {
      const int pos = (lw0+qq)*20 + ltp;
      const unsigned* kr = kbp + pos*6;
      uint2 ka = *reinterpret_cast<const uint2*>(kr);
      uint2 kb2= *reinterpret_cast<const uint2*>(kr+2);
      uint2 kc = *reinterpret_cast<const uint2*>(kr+4);
      float lg = __uint_as_float(((unsigned)br[qq]) << 16);
      lg += q0.x*BLO(ka.x) + q0.y*BHI(ka.x)
          + q0.z*BLO(ka.y) + q0.w*BHI(ka.y)
          + q1.x*BLO(kb2.x)+ q1.y*BHI(kb2.x)
          + q1.z*BLO(kb2.y)+ q1.w*BHI(kb2.y)
          + q2.x*BLO(kc.x) + q2.y*BHI(kc.x)
          + q2.z*BLO(kc.y) + q2.w*BHI(kc.y);
      float ex = __expf(lg);
      sum += ex;
      const unsigned* vr = vbp + pos*6;
      uint2 va = *reinterpret_cast<const uint2*>(vr);
      uint2 vb2= *reinterpret_cast<const uint2*>(vr+2);
      uint2 vc = *reinterpret_cast<const uint2*>(vr+4);
      o0  += ex*BLO(va.x);  o1  += ex*BHI(va.x);
      o2  += ex*BLO(va.y);  o3  += ex*BHI(va.y);
      o4  += ex*BLO(vb2.x); o5  += ex*BHI(vb2.x);
      o6  += ex*BLO(vb2.y); o7  += ex*BHI(vb2.y);
      o8  += ex*BLO(vc.x);  o9  += ex*BHI(vc.x);
      o10 += ex*BLO(vc.y);  o11 += ex*BHI(vc.y);
    }
  }
  sum += __shfl_xor(sum, 1);
  o0 += __shfl_xor(o0,1);  o1 += __shfl_xor(o1,1);
  o2 += __shfl_xor(o2,1);  o3 += __shfl_xor(o3,1);
  o4 += __shfl_xor(o4,1);  o5 += __shfl_xor(o5,1);
  o6 += __shfl_xor(o6,1);  o7 += __shfl_xor(o7,1);
  o8 += __shfl_xor(o8,1);  o9 += __shfl_xor(o9,1);
  o10 += __shfl_xor(o10,1);o11 += __shfl_xor(o11,1);
  if (e == 0) {
    float inv = 1.f/sum;
    float* ap = aol + pixidx*CD + head*HDIM;
    ap[0]=o0*inv;  ap[1]=o1*inv;  ap[2]=o2*inv;  ap[3]=o3*inv;
    ap[4]=o4*inv;  ap[5]=o5*inv;  ap[6]=o6*inv;  ap[7]=o7*inv;
    ap[8]=o8*inv;  ap[9]=o9*inv;  ap[10]=o10*inv; ap[11]=o11*inv;
  }
  __syncthreads();
  const int c = lane;
  const int pg = wv;
  if (c < CD) {
    const float bias = bproj[c];
    const float* wrow = wpl + c*49;
    float acc[8];
#pragma unroll
    for (int r=0;r<8;r++) acc[r]=bias;
#pragma unroll 1
    for (int i0=0; i0<CD; i0+=4) {
      float w0=wrow[i0], w1=wrow[i0+1], w2=wrow[i0+2], w3=wrow[i0+3];
#pragma unroll
      for (int r=0;r<8;r++) {
        float4 a4 = *reinterpret_cast<const float4*>(&aol[(pg*8+r)*CD + i0]);  // broadcast
        acc[r] += a4.x*w0 + a4.y*w1 + a4.z*w2 + a4.w*w3;
      }
    }
#pragma unroll
    for (int r=0;r<8;r++) {
      int px = pg*8 + r;
      int tt = t0 + (px & 7), ww = w0 + (px >> 3);
      dst[((size_t)tt*PD + ww)*CD + c] = acc[r];
    }
  }
}

extern "C" void kernel_launch(void* const* d_in, const int* in_sizes, int n_in,
                              void* d_out, int out_size, void* d_ws, size_t ws_size,
                              hipStream_t stream) {
  (void)in_sizes; (void)n_in; (void)out_size; (void)ws_size;
  const float* x        = (const float*)d_in[0];
  const float* w_ih_l0  = (const float*)d_in[1];
  const float* w_hh_l0  = (const float*)d_in[2];
  const float* b_ih_l0  = (const float*)d_in[3];
  const float* b_hh_l0  = (const float*)d_in[4];
  const float* w_ih_l0r = (const float*)d_in[5];
  const float* w_hh_l0r = (const float*)d_in[6];
  const float* b_ih_l0r = (const float*)d_in[7];
  const float* b_hh_l0r = (const float*)d_in[8];
  const float* w_ih_l1  = (const float*)d_in[9];
  const float* w_hh_l1  = (const float*)d_in[10];
  const float* b_ih_l1  = (const float*)d_in[11];
  const float* b_hh_l1  = (const float*)d_in[12];
  const float* w_ih_l1r = (const float*)d_in[13];
  const float* w_hh_l1r = (const float*)d_in[14];
  const float* b_ih_l1r = (const float*)d_in[15];
  const float* b_hh_l1r = (const float*)d_in[16];
  const float* w_qkv    = (const float*)d_in[17];
  const float* b_qkv    = (const float*)d_in[18];
  const float* rpb      = (const float*)d_in[19];
  const float* w_proj   = (const float*)d_in[20];
  const float* b_proj   = (const float*)d_in[21];
  float* out = (float*)d_out;

  float* ws = (float*)d_ws;
  const size_t NPIX = (size_t)TD*PD;
  float* XG = ws;
  float* Y  = XG + (size_t)2*PD*TD*GD;
  float* Qb = Y  + NPIX*CD;
  unsigned short* Kb = (unsigned short*)(Qb + NPIX*CD);
  unsigned short* Vb = Kb + NPIX*64;

  xg0_kernel<<<dim3(256,2),192,0,stream>>>(x, w_ih_l0, w_ih_l0r, b_ih_l0, b_hh_l0, b_ih_l0r, b_hh_l0r, XG);
  bilstm_kernel<<<PD,256,0,stream>>>(XG, w_hh_l0, w_hh_l0r,
                                     w_ih_l1, w_ih_l1r,
                                     b_ih_l1, b_hh_l1, b_ih_l1r, b_hh_l1r,
                                     w_hh_l1, w_hh_l1r, Y);

  for (int l=0; l<2; ++l) {
    qkv_kernel<<<352,192,0,stream>>>(Y, w_qkv, b_qkv, Qb, Kb, Vb);
    natten_kernel<<<176,512,0,stream>>>(Qb, Kb, Vb, rpb, w_proj, b_proj, (l==1)? out : Y);
  }
}